// Round 5
// baseline (415.167 us; speedup 1.0000x reference)
//
#include <hip/hip_runtime.h>
#include <hip/hip_fp16.h>

#define DIM 64
#define BPN 1024      // nodes per coarse bucket (10 bits)
#define ECHUNK 8192   // edges per scatter block (LDS staging = 32KB + 16KB map)
#define MAXNB 160     // padded bucket count (N=150k -> 147 buckets)

typedef _Float16 f16x8 __attribute__((ext_vector_type(8)));
typedef float f32x4 __attribute__((ext_vector_type(4)));

// ---------------------------------------------------------------------------
// GCN 2-layer forward. CSR built via locality-preserving two-level counting
// sort; per-edge {row, dinv[row]} packed once into 8B edata (shared by both
// layers). Aggregate: one wave per node, 8 lanes x float4 cover one 128B fp16
// row -> one wave-wide load serves 8 edges. Inner loop: groups 0-1 (16 slots)
// straight-line for MLP, groups 2-3 guarded by wave-uniform branches so
// low-degree nodes (avg d=20) skip dead slots (was 37% wasted VALU+VMEM).
// out = di * (sum coef_r * xw[r] + di * xw[i]) + b.
// ---------------------------------------------------------------------------

// Per-block LDS histogram of coarse buckets -> global bucket counts.
__global__ __launch_bounds__(1024) void bucket_count_kernel(
    const int* __restrict__ col, int* __restrict__ bucket_cnt, int E, int NB) {
  __shared__ int h[MAXNB];
  for (int t = threadIdx.x; t < NB; t += blockDim.x) h[t] = 0;
  __syncthreads();
  int base = blockIdx.x * ECHUNK;
  int end = min(base + ECHUNK, E);
  for (int e = base + (int)threadIdx.x; e < end; e += blockDim.x)
    atomicAdd(&h[col[e] >> 10], 1);
  __syncthreads();
  for (int t = threadIdx.x; t < NB; t += blockDim.x)
    if (h[t]) atomicAdd(&bucket_cnt[t], h[t]);
}

// Parallel scan of <=256 bucket counts (one block): shfl-scan + LDS combine.
__global__ __launch_bounds__(256) void bucket_scan_kernel(
    const int* __restrict__ bucket_cnt, int* __restrict__ bucket_base,
    int* __restrict__ bucket_cursor, int* __restrict__ off, int NB, int N, int E) {
  __shared__ int wsum[4];
  __shared__ int woff[4];
  const int t = threadIdx.x;
  const int lane = t & 63, wid = t >> 6;
  int v = (t < NB) ? bucket_cnt[t] : 0;
  int x = v;
#pragma unroll
  for (int d = 1; d < 64; d <<= 1) {
    int s = __shfl_up(x, d, 64);
    if (lane >= d) x += s;
  }
  if (lane == 63) wsum[wid] = x;
  __syncthreads();
  if (t == 0) {
    int s = 0;
#pragma unroll
    for (int k = 0; k < 4; k++) { woff[k] = s; s += wsum[k]; }
  }
  __syncthreads();
  int excl = woff[wid] + x - v;
  if (t < NB) { bucket_base[t] = excl; bucket_cursor[t] = excl; }
  if (t == 0) {
    bucket_base[NB] = woff[3] + wsum[3];
    off[N] = E;
  }
}

// LDS counting sort of an 8192-edge chunk by coarse bucket, then contiguous
// run writes per bucket (avg 56-elem runs -> near-full-line write efficiency).
__global__ __launch_bounds__(1024) void bucket_scatter_kernel(
    const int* __restrict__ row, const int* __restrict__ col,
    int* __restrict__ bucket_cursor, int* __restrict__ packed, int E, int NB) {
  __shared__ int h[MAXNB];
  __shared__ int excl0[MAXNB];
  __shared__ int cur[MAXNB];
  __shared__ int gbase[MAXNB];
  __shared__ int staging[ECHUNK];
  __shared__ unsigned short map[ECHUNK];
  const int tid = threadIdx.x;
  for (int t = tid; t < NB; t += blockDim.x) h[t] = 0;
  __syncthreads();
  int base = blockIdx.x * ECHUNK;
  int end = min(base + ECHUNK, E);
  int total = end - base;
  for (int e = base + tid; e < end; e += blockDim.x)
    atomicAdd(&h[col[e] >> 10], 1);
  __syncthreads();
  if (tid == 0) {
    int s = 0;
    for (int b = 0; b < NB; b++) { excl0[b] = s; cur[b] = s; s += h[b]; }
  }
  __syncthreads();
  if (tid < NB) {
    if (h[tid] > 0) gbase[tid] = atomicAdd(&bucket_cursor[tid], h[tid]);
    int s = excl0[tid], c = h[tid];
    for (int j = 0; j < c; j++) map[s + j] = (unsigned short)tid;
  }
  __syncthreads();
  for (int e = base + tid; e < end; e += blockDim.x) {
    int c = col[e];
    int b = c >> 10;
    int pos = atomicAdd(&cur[b], 1);
    staging[pos] = ((c & (BPN - 1)) << 18) | row[e];
  }
  __syncthreads();
  for (int idx = tid; idx < total; idx += blockDim.x) {
    int b = map[idx];
    packed[gbase[b] + idx - excl0[b]] = staging[idx];
  }
}

// One block per bucket: local 1024-bin histogram + scan -> off/dinv/perm_row
// (contiguous 4B scatter writes; coef pass is separate + fully coalesced).
__global__ __launch_bounds__(1024) void bucket_csr_kernel(
    const int* __restrict__ packed, const int* __restrict__ bucket_base,
    int* __restrict__ perm_row, int* __restrict__ off, float* __restrict__ dinv, int N) {
  __shared__ int nh[BPN];
  __shared__ int ncur[BPN];
  __shared__ int wsum[16];
  __shared__ int woff[16];
  const int b = blockIdx.x;
  const int tid = threadIdx.x;
  const int ebase = bucket_base[b];
  const int cnt = bucket_base[b + 1] - ebase;
  nh[tid] = 0;
  __syncthreads();
  for (int i = tid; i < cnt; i += 1024)
    atomicAdd(&nh[packed[ebase + i] >> 18], 1);
  __syncthreads();
  const int lane = tid & 63, wid = tid >> 6;
  int v = nh[tid], x = v;
#pragma unroll
  for (int d = 1; d < 64; d <<= 1) {
    int t = __shfl_up(x, d, 64);
    if (lane >= d) x += t;
  }
  if (lane == 63) wsum[wid] = x;
  __syncthreads();
  if (tid == 0) {
    int s = 0;
#pragma unroll
    for (int k = 0; k < 16; k++) { woff[k] = s; s += wsum[k]; }
  }
  __syncthreads();
  int excl = woff[wid] + x - v;
  ncur[tid] = excl;
  int node = b * BPN + tid;
  if (node < N) {
    off[node] = ebase + excl;
    dinv[node] = rsqrtf((float)v + 1.0f);
  }
  __syncthreads();
  for (int i = tid; i < cnt; i += 1024) {
    int p = packed[ebase + i];
    int local = p >> 18;
    int pos = atomicAdd(&ncur[local], 1);
    perm_row[ebase + pos] = p & 0x3FFFF;
  }
}

// Fill edata[e] = {row, dinv[row]} once (reused by both aggregate layers).
// Coalesced 4B read + coalesced 8B write; dinv gather hits the 600KB
// L2-resident table.
__global__ __launch_bounds__(256) void edge_coef_kernel(
    const int* __restrict__ perm_row, const float* __restrict__ dinv,
    int2* __restrict__ edata, int E) {
  int e = blockIdx.x * 256 + threadIdx.x;
  if (e >= E) return;
  int r = perm_row[e];
  edata[e] = make_int2(r, __float_as_int(dinv[r]));
}

// XW via MFMA: one wave computes a 16-row tile of xw = (relu?)(x) @ W.
// A-frag: lane holds x[rbase + (lane&15)][quad*8 .. +8] per k-step (f32->f16).
// B-frags: W^T staged in LDS f16 (stride 72: 2-way bank aliasing = free),
// preloaded once per block into 32 VGPRs. 8 MFMAs per 16 rows.
// Layer 1 (xb != null): x row r = concat(users, items)[r], also writes out0.
__global__ __launch_bounds__(256) void xw_mfma_kernel(
    const float* __restrict__ xa, const float* __restrict__ xb,
    const float* __restrict__ W, float* __restrict__ out0,
    __half* __restrict__ xwh, int NU, int N, int do_relu) {
  __shared__ _Float16 Wt[64 * 72];
  for (int t = threadIdx.x; t < 4096; t += 256) {
    int k = t >> 6, n = t & 63;
    Wt[n * 72 + k] = (_Float16)W[t];
  }
  __syncthreads();
  const int lane = threadIdx.x & 63;
  const int wid = threadIdx.x >> 6;
  const int m = lane & 15;     // A row within tile / B^T row (= W column)
  const int quad = lane >> 4;  // k-octet selector
  f16x8 bfrag[4][2];
#pragma unroll
  for (int c = 0; c < 4; c++)
#pragma unroll
    for (int s = 0; s < 2; s++)
      bfrag[c][s] = *(const f16x8*)&Wt[(c * 16 + m) * 72 + s * 32 + quad * 8];

  const int rbase = (blockIdx.x * 4 + wid) * 16;
  if (rbase >= N) return;
  const int r = rbase + m;
  const int rr = min(r, N - 1);
  const float* src = (xb == nullptr || rr < NU) ? xa + (size_t)rr * DIM
                                                : xb + (size_t)(rr - NU) * DIM;
  f16x8 afrag[2];
#pragma unroll
  for (int s = 0; s < 2; s++) {
    float4 u0 = *(const float4*)(src + s * 32 + quad * 8);
    float4 u1 = *(const float4*)(src + s * 32 + quad * 8 + 4);
    if (out0 != nullptr && r < N) {
      float4* o = (float4*)(out0 + (size_t)r * DIM);
      o[s * 8 + quad * 2] = u0;
      o[s * 8 + quad * 2 + 1] = u1;
    }
    if (do_relu) {
      u0.x = fmaxf(u0.x, 0.f); u0.y = fmaxf(u0.y, 0.f);
      u0.z = fmaxf(u0.z, 0.f); u0.w = fmaxf(u0.w, 0.f);
      u1.x = fmaxf(u1.x, 0.f); u1.y = fmaxf(u1.y, 0.f);
      u1.z = fmaxf(u1.z, 0.f); u1.w = fmaxf(u1.w, 0.f);
    }
    afrag[s][0] = (_Float16)u0.x; afrag[s][1] = (_Float16)u0.y;
    afrag[s][2] = (_Float16)u0.z; afrag[s][3] = (_Float16)u0.w;
    afrag[s][4] = (_Float16)u1.x; afrag[s][5] = (_Float16)u1.y;
    afrag[s][6] = (_Float16)u1.z; afrag[s][7] = (_Float16)u1.w;
  }
  f32x4 acc[4];
#pragma unroll
  for (int c = 0; c < 4; c++) {
    acc[c] = (f32x4){0.f, 0.f, 0.f, 0.f};
    acc[c] = __builtin_amdgcn_mfma_f32_16x16x32_f16(afrag[0], bfrag[c][0], acc[c], 0, 0, 0);
    acc[c] = __builtin_amdgcn_mfma_f32_16x16x32_f16(afrag[1], bfrag[c][1], acc[c], 0, 0, 0);
  }
  // D layout: row = quad*4 + reg, col = c*16 + m  (verified C/D mapping)
#pragma unroll
  for (int reg = 0; reg < 4; reg++) {
    int orow = rbase + quad * 4 + reg;
    if (orow < N) {
      __half* dst = xwh + (size_t)orow * DIM + m;
#pragma unroll
      for (int c = 0; c < 4; c++)
        dst[c * 16] = __float2half(acc[c][reg]);
    }
  }
}

// out[i] = di * ( sum_{r in nbrs(i)} coef_r * xw[r] + di * xw[i] ) + b
// 8 lanes x float4 cover one 128B fp16 row; lane loads its own edata entry.
// Per 32-slot chunk: groups 0-1 straight-line (MLP), groups 2-3 behind
// wave-uniform guards so avg-degree-20 nodes don't burn VALU/VMEM on dead
// slots. Clamped slots reread last edge's line with coef 0 (cache-hot).
__global__ void aggregate_kernel(const __half* __restrict__ xwh, const int* __restrict__ off,
                                 const int2* __restrict__ edata, const float* __restrict__ dinv,
                                 const float* __restrict__ b, float* __restrict__ out, int n) {
  const int lane = threadIdx.x & 63;
  const int i = blockIdx.x * (blockDim.x >> 6) + (threadIdx.x >> 6);
  if (i >= n) return;
  const int esel = lane >> 3;  // edge slot within a group: group g covers slots g*8+esel
  const int j = lane & 7;      // dim octet: dims 8j..8j+7
  const float di = dinv[i];
  const float4* rows = (const float4*)xwh;
  float acc[8];
#pragma unroll
  for (int q = 0; q < 8; q++) acc[q] = 0.0f;
  if (esel == 0) {  // self-loop as pseudo-edge with coef di (group 0 only)
    float4 f = rows[(size_t)i * 8 + j];
    const __half2* h = (const __half2*)&f;
#pragma unroll
    for (int q = 0; q < 4; q++) {
      float2 p = __half22float2(h[q]);
      acc[2 * q] = di * p.x;
      acc[2 * q + 1] = di * p.y;
    }
  }
  const int s0 = off[i], s1 = off[i + 1];
  const int last = s1 - 1;

#define ACC_GROUP(v, c, f)                                                 \
  {                                                                        \
    const __half2* hh = (const __half2*)&(f);                              \
    _Pragma("unroll") for (int q = 0; q < 4; q++) {                        \
      float2 p = __half22float2(hh[q]);                                    \
      acc[2 * q] += (c) * p.x;                                             \
      acc[2 * q + 1] += (c) * p.y;                                         \
    }                                                                      \
  }

  for (int k = s0; k < s1; k += 32) {
    const int rem = s1 - k;
    const int e0 = k + esel, e1 = e0 + 8;
    // groups 0-1: straight-line (clamped) for MLP
    int2 v0 = edata[min(e0, last)];
    int2 v1 = edata[min(e1, last)];
    float c0 = (e0 <= last) ? __int_as_float(v0.y) : 0.0f;
    float c1 = (e1 <= last) ? __int_as_float(v1.y) : 0.0f;
    float4 f0 = rows[(size_t)v0.x * 8 + j];
    float4 f1 = rows[(size_t)v1.x * 8 + j];
    ACC_GROUP(v0, c0, f0)
    ACC_GROUP(v1, c1, f1)
    // groups 2-3: wave-uniform guards (rem identical across the wave)
    if (rem > 16) {
      const int e2 = e0 + 16;
      int2 v2 = edata[min(e2, last)];
      float c2 = (e2 <= last) ? __int_as_float(v2.y) : 0.0f;
      float4 f2 = rows[(size_t)v2.x * 8 + j];
      ACC_GROUP(v2, c2, f2)
      if (rem > 24) {
        const int e3 = e0 + 24;
        int2 v3 = edata[min(e3, last)];
        float c3 = (e3 <= last) ? __int_as_float(v3.y) : 0.0f;
        float4 f3 = rows[(size_t)v3.x * 8 + j];
        ACC_GROUP(v3, c3, f3)
      }
    }
  }
#undef ACC_GROUP

#pragma unroll
  for (int q = 0; q < 8; q++) {
    acc[q] += __shfl_xor(acc[q], 8, 64);
    acc[q] += __shfl_xor(acc[q], 16, 64);
    acc[q] += __shfl_xor(acc[q], 32, 64);
  }
  if (esel == 0) {
    float4 b0 = ((const float4*)b)[2 * j];
    float4 b1 = ((const float4*)b)[2 * j + 1];
    float4* orow = (float4*)(out + (size_t)i * DIM);
    orow[2 * j] = make_float4(di * acc[0] + b0.x, di * acc[1] + b0.y,
                              di * acc[2] + b0.z, di * acc[3] + b0.w);
    orow[2 * j + 1] = make_float4(di * acc[4] + b1.x, di * acc[5] + b1.y,
                                  di * acc[6] + b1.z, di * acc[7] + b1.w);
  }
}

extern "C" void kernel_launch(void* const* d_in, const int* in_sizes, int n_in,
                              void* d_out, int out_size, void* d_ws, size_t ws_size,
                              hipStream_t stream) {
  const float* emb_users = (const float*)d_in[0];
  const float* emb_items = (const float*)d_in[1];
  const float* W1 = (const float*)d_in[2];
  const float* b1 = (const float*)d_in[3];
  const float* W2 = (const float*)d_in[4];
  const float* b2 = (const float*)d_in[5];
  const int* edge_index = (const int*)d_in[6];  // [2, E] int32 (JAX x64-off)
  // d_in[7] = edge_weight: accepted but unused by the reference forward.

  const int NU = in_sizes[0] / DIM;
  const int NI = in_sizes[1] / DIM;
  const int N = NU + NI;
  const int E = in_sizes[6] / 2;
  const int NB = (N + BPN - 1) / BPN;  // 147
  const int* row = edge_index;
  const int* col = edge_index + E;

  float* out = (float*)d_out;  // [3, N, DIM]

  char* ws = (char*)d_ws;
  size_t o = 0;
  auto alloc = [&](size_t bytes) -> void* {
    o = (o + 255) & ~(size_t)255;
    void* p = ws + o;
    o += bytes;
    return p;
  };
  int* bucket_cnt    = (int*)alloc((size_t)NB * 4);
  int* bucket_base   = (int*)alloc((size_t)(NB + 1) * 4);
  int* bucket_cursor = (int*)alloc((size_t)NB * 4);
  int* off           = (int*)alloc((size_t)(N + 1) * 4);
  float* dinv        = (float*)alloc((size_t)N * 4);
  int* perm_row      = (int*)alloc((size_t)E * 4);
  int2* edata        = (int2*)alloc((size_t)E * 8);
  __half* xwh        = (__half*)alloc((size_t)N * DIM * 2);
  int* packed        = (int*)xwh;  // overlay: dead before xwh is written
  (void)ws_size;

  const int nbE = (E + ECHUNK - 1) / ECHUNK;

  // --- CSR build (shared by both layers) ---
  hipMemsetAsync(bucket_cnt, 0, (size_t)NB * 4, stream);
  bucket_count_kernel<<<nbE, 1024, 0, stream>>>(col, bucket_cnt, E, NB);
  bucket_scan_kernel<<<1, 256, 0, stream>>>(bucket_cnt, bucket_base, bucket_cursor, off, NB, N, E);
  bucket_scatter_kernel<<<nbE, 1024, 0, stream>>>(row, col, bucket_cursor, packed, E, NB);
  bucket_csr_kernel<<<NB, 1024, 0, stream>>>(packed, bucket_base, perm_row, off, dinv, N);
  edge_coef_kernel<<<(E + 255) / 256, 256, 0, stream>>>(perm_row, dinv, edata, E);

  const int TB = 256;
  const int gr = (N + 3) / 4;            // aggregate: 4 waves/block, 1 node/wave
  const int gx = (N + 63) / 64;          // xw_mfma: 4 waves/block, 16 rows/wave

  // --- layer 1: out0 = concat(emb); xw = out0 @ W1; out1 = aggregate + b1 ---
  xw_mfma_kernel<<<gx, TB, 0, stream>>>(emb_users, emb_items, W1, out, xwh, NU, N, 0);
  aggregate_kernel<<<gr, TB, 0, stream>>>((const __half*)xwh, off, edata, dinv, b1,
                                          out + (size_t)N * DIM, N);

  // --- layer 2: xw = relu(out1) @ W2; out2 = aggregate + b2 ---
  xw_mfma_kernel<<<gx, TB, 0, stream>>>(out + (size_t)N * DIM, nullptr, W2, nullptr, xwh, N, N, 1);
  aggregate_kernel<<<gr, TB, 0, stream>>>((const __half*)xwh, off, edata, dinv, b2,
                                          out + (size_t)2 * N * DIM, N);
}

// Round 6
// 404.356 us; speedup vs baseline: 1.0267x; 1.0267x over previous
//
#include <hip/hip_runtime.h>
#include <hip/hip_fp16.h>

#define DIM 64
#define BPN 1024      // nodes per coarse bucket (10 bits)
#define ECHUNK 8192   // edges per scatter block (LDS staging = 32KB + 16KB map)
#define MAXNB 160     // padded bucket count (N=150k -> 147 buckets)

typedef _Float16 f16x8 __attribute__((ext_vector_type(8)));
typedef float f32x4 __attribute__((ext_vector_type(4)));

// ---------------------------------------------------------------------------
// GCN 2-layer forward. CSR built via locality-preserving two-level counting
// sort; per-edge {row, dinv[row]} packed once into 8B edata (shared by both
// layers). Aggregate: one wave per node, 8 lanes x float4 cover one 128B fp16
// row -> one wave-wide load serves 8 edges; straight-line x4 unroll (round-3
// shape: best measured; guards and deeper unrolls both regressed -> gather is
// L2-miss-throughput-bound). Aggregate launched as 2 half-range dispatches
// per layer so build kernels surface in the profiler's top-5.
// out = di * (sum coef_r * xw[r] + di * xw[i]) + b.
// ---------------------------------------------------------------------------

// Per-block LDS histogram of coarse buckets -> global bucket counts.
__global__ __launch_bounds__(1024) void bucket_count_kernel(
    const int* __restrict__ col, int* __restrict__ bucket_cnt, int E, int NB) {
  __shared__ int h[MAXNB];
  for (int t = threadIdx.x; t < NB; t += blockDim.x) h[t] = 0;
  __syncthreads();
  int base = blockIdx.x * ECHUNK;
  int end = min(base + ECHUNK, E);
  for (int e = base + (int)threadIdx.x; e < end; e += blockDim.x)
    atomicAdd(&h[col[e] >> 10], 1);
  __syncthreads();
  for (int t = threadIdx.x; t < NB; t += blockDim.x)
    if (h[t]) atomicAdd(&bucket_cnt[t], h[t]);
}

// Parallel scan of <=256 bucket counts (one block): shfl-scan + LDS combine.
__global__ __launch_bounds__(256) void bucket_scan_kernel(
    const int* __restrict__ bucket_cnt, int* __restrict__ bucket_base,
    int* __restrict__ bucket_cursor, int* __restrict__ off, int NB, int N, int E) {
  __shared__ int wsum[4];
  __shared__ int woff[4];
  const int t = threadIdx.x;
  const int lane = t & 63, wid = t >> 6;
  int v = (t < NB) ? bucket_cnt[t] : 0;
  int x = v;
#pragma unroll
  for (int d = 1; d < 64; d <<= 1) {
    int s = __shfl_up(x, d, 64);
    if (lane >= d) x += s;
  }
  if (lane == 63) wsum[wid] = x;
  __syncthreads();
  if (t == 0) {
    int s = 0;
#pragma unroll
    for (int k = 0; k < 4; k++) { woff[k] = s; s += wsum[k]; }
  }
  __syncthreads();
  int excl = woff[wid] + x - v;
  if (t < NB) { bucket_base[t] = excl; bucket_cursor[t] = excl; }
  if (t == 0) {
    bucket_base[NB] = woff[3] + wsum[3];
    off[N] = E;
  }
}

// LDS counting sort of an 8192-edge chunk by coarse bucket, then contiguous
// run writes per bucket (avg 56-elem runs -> near-full-line write efficiency).
// Local histogram scan parallelized (16-wave shfl scan; was 1-thread serial).
__global__ __launch_bounds__(1024) void bucket_scatter_kernel(
    const int* __restrict__ row, const int* __restrict__ col,
    int* __restrict__ bucket_cursor, int* __restrict__ packed, int E, int NB) {
  __shared__ int h[MAXNB];
  __shared__ int excl0[MAXNB];
  __shared__ int cur[MAXNB];
  __shared__ int gbase[MAXNB];
  __shared__ int wsum[16];
  __shared__ int woff[16];
  __shared__ int staging[ECHUNK];
  __shared__ unsigned short map[ECHUNK];
  const int tid = threadIdx.x;
  for (int t = tid; t < NB; t += blockDim.x) h[t] = 0;
  __syncthreads();
  int base = blockIdx.x * ECHUNK;
  int end = min(base + ECHUNK, E);
  int total = end - base;
  for (int e = base + tid; e < end; e += blockDim.x)
    atomicAdd(&h[col[e] >> 10], 1);
  __syncthreads();
  {  // parallel exclusive scan of h[0..NB) across 16 waves
    const int lane = tid & 63, wid = tid >> 6;
    int v = (tid < NB) ? h[tid] : 0;
    int x = v;
#pragma unroll
    for (int d = 1; d < 64; d <<= 1) {
      int s = __shfl_up(x, d, 64);
      if (lane >= d) x += s;
    }
    if (lane == 63) wsum[wid] = x;
    __syncthreads();
    if (tid == 0) {
      int s = 0;
#pragma unroll
      for (int k = 0; k < 16; k++) { woff[k] = s; s += wsum[k]; }
    }
    __syncthreads();
    if (tid < NB) {
      int excl = woff[wid] + x - v;
      excl0[tid] = excl;
      cur[tid] = excl;
    }
  }
  __syncthreads();
  if (tid < NB) {
    if (h[tid] > 0) gbase[tid] = atomicAdd(&bucket_cursor[tid], h[tid]);
    int s = excl0[tid], c = h[tid];
    for (int j = 0; j < c; j++) map[s + j] = (unsigned short)tid;
  }
  __syncthreads();
  for (int e = base + tid; e < end; e += blockDim.x) {
    int c = col[e];
    int b = c >> 10;
    int pos = atomicAdd(&cur[b], 1);
    staging[pos] = ((c & (BPN - 1)) << 18) | row[e];
  }
  __syncthreads();
  for (int idx = tid; idx < total; idx += blockDim.x) {
    int b = map[idx];
    packed[gbase[b] + idx - excl0[b]] = staging[idx];
  }
}

// One block per bucket: local 1024-bin histogram + scan -> off/dinv/perm_row
// (contiguous 4B scatter writes; coef pass is separate + fully coalesced).
__global__ __launch_bounds__(1024) void bucket_csr_kernel(
    const int* __restrict__ packed, const int* __restrict__ bucket_base,
    int* __restrict__ perm_row, int* __restrict__ off, float* __restrict__ dinv, int N) {
  __shared__ int nh[BPN];
  __shared__ int ncur[BPN];
  __shared__ int wsum[16];
  __shared__ int woff[16];
  const int b = blockIdx.x;
  const int tid = threadIdx.x;
  const int ebase = bucket_base[b];
  const int cnt = bucket_base[b + 1] - ebase;
  nh[tid] = 0;
  __syncthreads();
  for (int i = tid; i < cnt; i += 1024)
    atomicAdd(&nh[packed[ebase + i] >> 18], 1);
  __syncthreads();
  const int lane = tid & 63, wid = tid >> 6;
  int v = nh[tid], x = v;
#pragma unroll
  for (int d = 1; d < 64; d <<= 1) {
    int t = __shfl_up(x, d, 64);
    if (lane >= d) x += t;
  }
  if (lane == 63) wsum[wid] = x;
  __syncthreads();
  if (tid == 0) {
    int s = 0;
#pragma unroll
    for (int k = 0; k < 16; k++) { woff[k] = s; s += wsum[k]; }
  }
  __syncthreads();
  int excl = woff[wid] + x - v;
  ncur[tid] = excl;
  int node = b * BPN + tid;
  if (node < N) {
    off[node] = ebase + excl;
    dinv[node] = rsqrtf((float)v + 1.0f);
  }
  __syncthreads();
  for (int i = tid; i < cnt; i += 1024) {
    int p = packed[ebase + i];
    int local = p >> 18;
    int pos = atomicAdd(&ncur[local], 1);
    perm_row[ebase + pos] = p & 0x3FFFF;
  }
}

// Fill edata[e] = {row, dinv[row]} once (reused by both aggregate layers).
// Coalesced 4B read + coalesced 8B write; dinv gather hits the 600KB
// L2-resident table.
__global__ __launch_bounds__(256) void edge_coef_kernel(
    const int* __restrict__ perm_row, const float* __restrict__ dinv,
    int2* __restrict__ edata, int E) {
  int e = blockIdx.x * 256 + threadIdx.x;
  if (e >= E) return;
  int r = perm_row[e];
  edata[e] = make_int2(r, __float_as_int(dinv[r]));
}

// XW via MFMA: one wave computes a 16-row tile of xw = (relu?)(x) @ W.
// A-frag: lane holds x[rbase + (lane&15)][quad*8 .. +8] per k-step (f32->f16).
// B-frags: W^T staged in LDS f16 (stride 72: 2-way bank aliasing = free),
// preloaded once per block into 32 VGPRs. 8 MFMAs per 16 rows.
// Layer 1 (xb != null): x row r = concat(users, items)[r], also writes out0.
__global__ __launch_bounds__(256) void xw_mfma_kernel(
    const float* __restrict__ xa, const float* __restrict__ xb,
    const float* __restrict__ W, float* __restrict__ out0,
    __half* __restrict__ xwh, int NU, int N, int do_relu) {
  __shared__ _Float16 Wt[64 * 72];
  for (int t = threadIdx.x; t < 4096; t += 256) {
    int k = t >> 6, n = t & 63;
    Wt[n * 72 + k] = (_Float16)W[t];
  }
  __syncthreads();
  const int lane = threadIdx.x & 63;
  const int wid = threadIdx.x >> 6;
  const int m = lane & 15;     // A row within tile / B^T row (= W column)
  const int quad = lane >> 4;  // k-octet selector
  f16x8 bfrag[4][2];
#pragma unroll
  for (int c = 0; c < 4; c++)
#pragma unroll
    for (int s = 0; s < 2; s++)
      bfrag[c][s] = *(const f16x8*)&Wt[(c * 16 + m) * 72 + s * 32 + quad * 8];

  const int rbase = (blockIdx.x * 4 + wid) * 16;
  if (rbase >= N) return;
  const int r = rbase + m;
  const int rr = min(r, N - 1);
  const float* src = (xb == nullptr || rr < NU) ? xa + (size_t)rr * DIM
                                                : xb + (size_t)(rr - NU) * DIM;
  f16x8 afrag[2];
#pragma unroll
  for (int s = 0; s < 2; s++) {
    float4 u0 = *(const float4*)(src + s * 32 + quad * 8);
    float4 u1 = *(const float4*)(src + s * 32 + quad * 8 + 4);
    if (out0 != nullptr && r < N) {
      float4* o = (float4*)(out0 + (size_t)r * DIM);
      o[s * 8 + quad * 2] = u0;
      o[s * 8 + quad * 2 + 1] = u1;
    }
    if (do_relu) {
      u0.x = fmaxf(u0.x, 0.f); u0.y = fmaxf(u0.y, 0.f);
      u0.z = fmaxf(u0.z, 0.f); u0.w = fmaxf(u0.w, 0.f);
      u1.x = fmaxf(u1.x, 0.f); u1.y = fmaxf(u1.y, 0.f);
      u1.z = fmaxf(u1.z, 0.f); u1.w = fmaxf(u1.w, 0.f);
    }
    afrag[s][0] = (_Float16)u0.x; afrag[s][1] = (_Float16)u0.y;
    afrag[s][2] = (_Float16)u0.z; afrag[s][3] = (_Float16)u0.w;
    afrag[s][4] = (_Float16)u1.x; afrag[s][5] = (_Float16)u1.y;
    afrag[s][6] = (_Float16)u1.z; afrag[s][7] = (_Float16)u1.w;
  }
  f32x4 acc[4];
#pragma unroll
  for (int c = 0; c < 4; c++) {
    acc[c] = (f32x4){0.f, 0.f, 0.f, 0.f};
    acc[c] = __builtin_amdgcn_mfma_f32_16x16x32_f16(afrag[0], bfrag[c][0], acc[c], 0, 0, 0);
    acc[c] = __builtin_amdgcn_mfma_f32_16x16x32_f16(afrag[1], bfrag[c][1], acc[c], 0, 0, 0);
  }
  // D layout: row = quad*4 + reg, col = c*16 + m  (verified C/D mapping)
#pragma unroll
  for (int reg = 0; reg < 4; reg++) {
    int orow = rbase + quad * 4 + reg;
    if (orow < N) {
      __half* dst = xwh + (size_t)orow * DIM + m;
#pragma unroll
      for (int c = 0; c < 4; c++)
        dst[c * 16] = __float2half(acc[c][reg]);
    }
  }
}

// out[i] = di * ( sum_{r in nbrs(i)} coef_r * xw[r] + di * xw[i] ) + b
// 8 lanes x float4 cover one 128B fp16 row; lane loads its own edata entry
// (8 lanes share one 8B address -> broadcast; sequential lines across iters).
// Straight-line x4 (round-3 shape). Node range [nbase, nbase+ncnt) so the
// launch can be split into halves (profiler visibility + no perf cost).
__global__ void aggregate_kernel(const __half* __restrict__ xwh, const int* __restrict__ off,
                                 const int2* __restrict__ edata, const float* __restrict__ dinv,
                                 const float* __restrict__ b, float* __restrict__ out,
                                 int nbase, int ncnt) {
  const int lane = threadIdx.x & 63;
  const int li = blockIdx.x * (blockDim.x >> 6) + (threadIdx.x >> 6);
  if (li >= ncnt) return;
  const int i = nbase + li;
  const int esel = lane >> 3;  // edge slot within a 32-edge iteration: esel, esel+8, ...
  const int j = lane & 7;      // dim octet: dims 8j..8j+7
  const float di = dinv[i];
  const float4* rows = (const float4*)xwh;
  float acc[8];
#pragma unroll
  for (int q = 0; q < 8; q++) acc[q] = 0.0f;
  if (esel == 0) {  // self-loop as pseudo-edge with coef di (group 0 only)
    float4 f = rows[(size_t)i * 8 + j];
    const __half2* h = (const __half2*)&f;
#pragma unroll
    for (int q = 0; q < 4; q++) {
      float2 p = __half22float2(h[q]);
      acc[2 * q] = di * p.x;
      acc[2 * q + 1] = di * p.y;
    }
  }
  const int s0 = off[i], s1 = off[i + 1];
  const int last = s1 - 1;
  for (int k = s0; k < s1; k += 32) {
    const int e0 = k + esel, e1 = e0 + 8, e2 = e0 + 16, e3 = e0 + 24;
    int2 v0 = edata[min(e0, last)];
    int2 v1 = edata[min(e1, last)];
    int2 v2 = edata[min(e2, last)];
    int2 v3 = edata[min(e3, last)];
    float c0 = (e0 <= last) ? __int_as_float(v0.y) : 0.0f;
    float c1 = (e1 <= last) ? __int_as_float(v1.y) : 0.0f;
    float c2 = (e2 <= last) ? __int_as_float(v2.y) : 0.0f;
    float c3 = (e3 <= last) ? __int_as_float(v3.y) : 0.0f;
    float4 f0 = rows[(size_t)v0.x * 8 + j];
    float4 f1 = rows[(size_t)v1.x * 8 + j];
    float4 f2 = rows[(size_t)v2.x * 8 + j];
    float4 f3 = rows[(size_t)v3.x * 8 + j];
    const __half2* h0 = (const __half2*)&f0;
    const __half2* h1 = (const __half2*)&f1;
    const __half2* h2 = (const __half2*)&f2;
    const __half2* h3 = (const __half2*)&f3;
#pragma unroll
    for (int q = 0; q < 4; q++) {
      float2 p0 = __half22float2(h0[q]);
      acc[2 * q] += c0 * p0.x;
      acc[2 * q + 1] += c0 * p0.y;
    }
#pragma unroll
    for (int q = 0; q < 4; q++) {
      float2 p1 = __half22float2(h1[q]);
      acc[2 * q] += c1 * p1.x;
      acc[2 * q + 1] += c1 * p1.y;
    }
#pragma unroll
    for (int q = 0; q < 4; q++) {
      float2 p2 = __half22float2(h2[q]);
      acc[2 * q] += c2 * p2.x;
      acc[2 * q + 1] += c2 * p2.y;
    }
#pragma unroll
    for (int q = 0; q < 4; q++) {
      float2 p3 = __half22float2(h3[q]);
      acc[2 * q] += c3 * p3.x;
      acc[2 * q + 1] += c3 * p3.y;
    }
  }
#pragma unroll
  for (int q = 0; q < 8; q++) {
    acc[q] += __shfl_xor(acc[q], 8, 64);
    acc[q] += __shfl_xor(acc[q], 16, 64);
    acc[q] += __shfl_xor(acc[q], 32, 64);
  }
  if (esel == 0) {
    float4 b0 = ((const float4*)b)[2 * j];
    float4 b1 = ((const float4*)b)[2 * j + 1];
    float4* orow = (float4*)(out + (size_t)i * DIM);
    orow[2 * j] = make_float4(di * acc[0] + b0.x, di * acc[1] + b0.y,
                              di * acc[2] + b0.z, di * acc[3] + b0.w);
    orow[2 * j + 1] = make_float4(di * acc[4] + b1.x, di * acc[5] + b1.y,
                                  di * acc[6] + b1.z, di * acc[7] + b1.w);
  }
}

extern "C" void kernel_launch(void* const* d_in, const int* in_sizes, int n_in,
                              void* d_out, int out_size, void* d_ws, size_t ws_size,
                              hipStream_t stream) {
  const float* emb_users = (const float*)d_in[0];
  const float* emb_items = (const float*)d_in[1];
  const float* W1 = (const float*)d_in[2];
  const float* b1 = (const float*)d_in[3];
  const float* W2 = (const float*)d_in[4];
  const float* b2 = (const float*)d_in[5];
  const int* edge_index = (const int*)d_in[6];  // [2, E] int32 (JAX x64-off)
  // d_in[7] = edge_weight: accepted but unused by the reference forward.

  const int NU = in_sizes[0] / DIM;
  const int NI = in_sizes[1] / DIM;
  const int N = NU + NI;
  const int E = in_sizes[6] / 2;
  const int NB = (N + BPN - 1) / BPN;  // 147
  const int* row = edge_index;
  const int* col = edge_index + E;

  float* out = (float*)d_out;  // [3, N, DIM]

  char* ws = (char*)d_ws;
  size_t o = 0;
  auto alloc = [&](size_t bytes) -> void* {
    o = (o + 255) & ~(size_t)255;
    void* p = ws + o;
    o += bytes;
    return p;
  };
  int* bucket_cnt    = (int*)alloc((size_t)NB * 4);
  int* bucket_base   = (int*)alloc((size_t)(NB + 1) * 4);
  int* bucket_cursor = (int*)alloc((size_t)NB * 4);
  int* off           = (int*)alloc((size_t)(N + 1) * 4);
  float* dinv        = (float*)alloc((size_t)N * 4);
  int* perm_row      = (int*)alloc((size_t)E * 4);
  int2* edata        = (int2*)alloc((size_t)E * 8);
  __half* xwh        = (__half*)alloc((size_t)N * DIM * 2);
  int* packed        = (int*)xwh;  // overlay: dead before xwh is written
  (void)ws_size;

  const int nbE = (E + ECHUNK - 1) / ECHUNK;

  // --- CSR build (shared by both layers) ---
  hipMemsetAsync(bucket_cnt, 0, (size_t)NB * 4, stream);
  bucket_count_kernel<<<nbE, 1024, 0, stream>>>(col, bucket_cnt, E, NB);
  bucket_scan_kernel<<<1, 256, 0, stream>>>(bucket_cnt, bucket_base, bucket_cursor, off, NB, N, E);
  bucket_scatter_kernel<<<nbE, 1024, 0, stream>>>(row, col, bucket_cursor, packed, E, NB);
  bucket_csr_kernel<<<NB, 1024, 0, stream>>>(packed, bucket_base, perm_row, off, dinv, N);
  edge_coef_kernel<<<(E + 255) / 256, 256, 0, stream>>>(perm_row, dinv, edata, E);

  const int TB = 256;
  const int gx = (N + 63) / 64;          // xw_mfma: 4 waves/block, 16 rows/wave
  const int NH = (N + 1) / 2;            // aggregate split point (half range)
  const int g1 = (NH + 3) / 4;           // aggregate: 4 waves/block, 1 node/wave
  const int g2 = (N - NH + 3) / 4;

  // --- layer 1: out0 = concat(emb); xw = out0 @ W1; out1 = aggregate + b1 ---
  xw_mfma_kernel<<<gx, TB, 0, stream>>>(emb_users, emb_items, W1, out, xwh, NU, N, 0);
  aggregate_kernel<<<g1, TB, 0, stream>>>((const __half*)xwh, off, edata, dinv, b1,
                                          out + (size_t)N * DIM, 0, NH);
  aggregate_kernel<<<g2, TB, 0, stream>>>((const __half*)xwh, off, edata, dinv, b1,
                                          out + (size_t)N * DIM, NH, N - NH);

  // --- layer 2: xw = relu(out1) @ W2; out2 = aggregate + b2 ---
  xw_mfma_kernel<<<gx, TB, 0, stream>>>(out + (size_t)N * DIM, nullptr, W2, nullptr, xwh, N, N, 1);
  aggregate_kernel<<<g1, TB, 0, stream>>>((const __half*)xwh, off, edata, dinv, b2,
                                          out + (size_t)2 * N * DIM, 0, NH);
  aggregate_kernel<<<g2, TB, 0, stream>>>((const __half*)xwh, off, edata, dinv, b2,
                                          out + (size_t)2 * N * DIM, NH, N - NH);
}